// Round 6
// baseline (299.691 us; speedup 1.0000x reference)
//
#include <hip/hip_runtime.h>
#include <math.h>

typedef __bf16 bf16x8 __attribute__((ext_vector_type(8)));
typedef __bf16 bf16x4 __attribute__((ext_vector_type(4)));
typedef float  f32x4  __attribute__((ext_vector_type(4)));

// N=2, Q=1600, K=100, C=256, h=8, d=32.
// ---- workspace layout (float offsets), total 2,083,104 f32 = 8.33 MB ----
#define WS_KH    0u        // [200][256] f32 k projection              -> 51200
#define WS_VH    51200u    // [200][256] f32 v projection              -> 102400
#define WS_EWT   102400u   // [258][256] f32 embed_w TRANSPOSED [j][c] -> 168448
#define WS_OWT   168448u   // [256][256] f32 out_w TRANSPOSED [j][c]   -> 233984
#define WS_QHB   233984u   // bf16 [3200][256] scaled q projection     -> 643584
#define WS_BIASB 643584u   // bf16 [3200][100][8] rel-pos bias         -> 1923584
#define WS_KEB   1923584u  // bf16 [200][264] key sin/cos (pad 264)    -> 1949984
#define WS_W1B   1949984u  // bf16 [256][256] pos_w1                   -> 1982752
#define WS_W2PB  1982752u  // bf16 [16][256] pos_w2 padded             -> 1984800
#define WS_IPWT  1984800u  // bf16 [256][768] in_proj_w TRANSPOSED     -> 2083104

__device__ __forceinline__ float rdlane(float v, int l) {
  return __uint_as_float(__builtin_amdgcn_readlane(__float_as_uint(v), l));
}

// ---------------------------------------------------------------------------
// prep1: keb table, bf16 casts, and the three weight transposes (LDS tiles)
__global__ __launch_bounds__(256) void prep1_kernel(
    const float* __restrict__ kpos,
    const float* __restrict__ pos_w1, const float* __restrict__ pos_w2,
    const float* __restrict__ embed_w, const float* __restrict__ out_w,
    const float* __restrict__ ipw, float* __restrict__ ws)
{
  __shared__ float tile[64 * 65];
  int bid = blockIdx.x, t = threadIdx.x;

  if (bid < 50) {
    int r = bid * 4 + (t >> 6);
    int u = t & 63;
    float p0 = kpos[r * 2 + 0], p1 = kpos[r * 2 + 1];
    __bf16* keb = (__bf16*)(ws + WS_KEB);
    bf16x4 o;
#pragma unroll
    for (int j = 0; j < 4; j++) {
      int col = u * 4 + j;
      int c = col >> 7, i = (col & 127) >> 1;
      float p = c ? p1 : p0;
      float inv = exp2f((float)i * (-13.287712379549449f / 64.0f));
      float v = p * inv;
      o[j] = (__bf16)((col & 1) ? __cosf(v) : __sinf(v));
    }
    *(bf16x4*)(keb + r * 264 + u * 4) = o;
  } else if (bid < 114) {
    int idx = (bid - 50) * 1024 + t * 4;
    float4 v = *(const float4*)(pos_w1 + idx);
    bf16x4 o; o[0] = (__bf16)v.x; o[1] = (__bf16)v.y; o[2] = (__bf16)v.z; o[3] = (__bf16)v.w;
    *(bf16x4*)((__bf16*)(ws + WS_W1B) + idx) = o;
  } else if (bid == 114) {
    __bf16* w2pb = (__bf16*)(ws + WS_W2PB);
    for (int i = 0; i < 16; i++) {
      int idx = t * 16 + i;
      w2pb[idx] = (idx < 2048) ? (__bf16)pos_w2[idx] : (__bf16)0.0f;
    }
  } else if (bid < 135) {
    // EWT: embed_w [256 c][258 j] -> ewT f32 [j][c]
    int idx = bid - 115;
    int j0 = (idx / 4) * 64, c0 = (idx % 4) * 64;
    int jj = t & 63, rq = t >> 6;
    for (int rr = 0; rr < 16; rr++) {
      int c = rr * 4 + rq;
      float v = (j0 + jj < 258) ? embed_w[(c0 + c) * 258 + j0 + jj] : 0.0f;
      tile[c * 65 + jj] = v;
    }
    __syncthreads();
    int cc = t & 63, jq = t >> 6;
    for (int pp = 0; pp < 16; pp++) {
      int j = pp * 4 + jq;
      if (j0 + j < 258)
        ws[WS_EWT + (unsigned)(j0 + j) * 256u + c0 + cc] = tile[cc * 65 + j];
    }
  } else if (bid < 151) {
    // OWT: out_w [256 c][256 j] -> owT f32 [j][c]
    int idx = bid - 135;
    int j0 = (idx >> 2) * 64, c0 = (idx & 3) * 64;
    int jj = t & 63, rq = t >> 6;
    for (int rr = 0; rr < 16; rr++) {
      int c = rr * 4 + rq;
      tile[c * 65 + jj] = out_w[(c0 + c) * 256 + j0 + jj];
    }
    __syncthreads();
    int cc = t & 63, jq = t >> 6;
    for (int pp = 0; pp < 16; pp++) {
      int j = pp * 4 + jq;
      ws[WS_OWT + (unsigned)(j0 + j) * 256u + c0 + cc] = tile[cc * 65 + j];
    }
  } else {
    // IPWT: ipw [768 o][256 j] -> ipwT bf16 [j][768 o]
    int idx = bid - 151;                 // 48 blocks
    int j0 = (idx & 3) * 64, o0 = (idx >> 2) * 64;
    int jj = t & 63, rq = t >> 6;
    for (int rr = 0; rr < 16; rr++) {
      int o = rr * 4 + rq;
      tile[o * 65 + jj] = ipw[(unsigned)(o0 + o) * 256u + j0 + jj];
    }
    __syncthreads();
    __bf16* ipwt = (__bf16*)(ws + WS_IPWT);
    int oo = t & 63, jq = t >> 6;
    for (int pp = 0; pp < 16; pp++) {
      int j = pp * 4 + jq;
      ipwt[(unsigned)(j0 + j) * 768u + o0 + oo] = (__bf16)tile[oo * 65 + j];
    }
  }
}

// ---------------------------------------------------------------------------
// prep2: q/k/v projections with coalesced transposed-weight reads
__global__ __launch_bounds__(256, 2) void prep2_kernel(
    const float* __restrict__ qfeat, const float* __restrict__ kfeat,
    const float* __restrict__ ipb, float* __restrict__ ws)
{
  __shared__ float x[8 * 256];
  int bid = blockIdx.x, t = threadIdx.x;
  const __bf16* ipwt = (const __bf16*)(ws + WS_IPWT);

  if (bid < 400) {
    int r0 = bid * 8;
    for (int i = t; i < 2048; i += 256) x[i] = qfeat[(unsigned)r0 * 256u + i];
    __syncthreads();
    float acc[8]; float bq = ipb[t];
#pragma unroll
    for (int rr = 0; rr < 8; rr++) acc[rr] = bq;
#pragma unroll 4
    for (int j = 0; j < 256; j += 4) {
      float w0 = (float)ipwt[(unsigned)(j + 0) * 768u + t];
      float w1 = (float)ipwt[(unsigned)(j + 1) * 768u + t];
      float w2 = (float)ipwt[(unsigned)(j + 2) * 768u + t];
      float w3 = (float)ipwt[(unsigned)(j + 3) * 768u + t];
#pragma unroll
      for (int rr = 0; rr < 8; rr++) {
        float4 x4 = *(const float4*)(x + rr * 256 + j);
        acc[rr] = fmaf(x4.x, w0, fmaf(x4.y, w1, fmaf(x4.z, w2, fmaf(x4.w, w3, acc[rr]))));
      }
    }
    __bf16* qhb = (__bf16*)(ws + WS_QHB);
#pragma unroll
    for (int rr = 0; rr < 8; rr++)
      qhb[(unsigned)(r0 + rr) * 256u + t] = (__bf16)(acc[rr] * 0.17677669529663687f);
  } else {
    int b2 = bid - 400; int n = b2 >> 4, tileI = b2 & 15;
    int r0l = tileI * 7; int cnt = 100 - r0l; if (cnt > 7) cnt = 7; if (cnt <= 0) return;
    int r0 = n * 100 + r0l;
    for (int i = t; i < cnt * 256; i += 256) x[i] = kfeat[(unsigned)r0 * 256u + i];
    __syncthreads();
    float ak[7], av[7]; float bk = ipb[256 + t], bv = ipb[512 + t];
#pragma unroll
    for (int rr = 0; rr < 7; rr++) { ak[rr] = bk; av[rr] = bv; }
#pragma unroll 2
    for (int j = 0; j < 256; j += 4) {
      float wk0 = (float)ipwt[(unsigned)(j + 0) * 768u + 256 + t];
      float wk1 = (float)ipwt[(unsigned)(j + 1) * 768u + 256 + t];
      float wk2 = (float)ipwt[(unsigned)(j + 2) * 768u + 256 + t];
      float wk3 = (float)ipwt[(unsigned)(j + 3) * 768u + 256 + t];
      float wv0 = (float)ipwt[(unsigned)(j + 0) * 768u + 512 + t];
      float wv1 = (float)ipwt[(unsigned)(j + 1) * 768u + 512 + t];
      float wv2 = (float)ipwt[(unsigned)(j + 2) * 768u + 512 + t];
      float wv3 = (float)ipwt[(unsigned)(j + 3) * 768u + 512 + t];
#pragma unroll
      for (int rr = 0; rr < 7; rr++) {
        float4 x4 = *(const float4*)(x + rr * 256 + j);
        ak[rr] = fmaf(x4.x, wk0, fmaf(x4.y, wk1, fmaf(x4.z, wk2, fmaf(x4.w, wk3, ak[rr]))));
        av[rr] = fmaf(x4.x, wv0, fmaf(x4.y, wv1, fmaf(x4.z, wv2, fmaf(x4.w, wv3, av[rr]))));
      }
    }
    for (int rr = 0; rr < 7; rr++) {
      if (rr < cnt) {
        ws[WS_KH + (unsigned)(r0 + rr) * 256u + t] = ak[rr];
        ws[WS_VH + (unsigned)(r0 + rr) * 256u + t] = av[rr];
      }
    }
  }
}

// ---------------------------------------------------------------------------
// bias kernel v5: Qb=4, 512 threads, grid 800. Software-pipelined gen:
// gen_load (keb/qe -> regs) issues BEFORE the MFMA loop, gen_store after.
__global__ __launch_bounds__(512) void bias_kernel(
    const float* __restrict__ qpos,
    const float* __restrict__ pos_b1, const float* __restrict__ pos_b2,
    float* __restrict__ ws)
{
  __shared__ __align__(16) char smem[63488];
  __bf16* qe_s   = (__bf16*)(smem + 28672);
  __bf16* region = (__bf16*)(smem + 30720);

  int bid = blockIdx.x;
  int n = bid / 400;
  int q0 = bid * 4;
  int t = threadIdx.x;
  int lane = t & 63, w = t >> 6;
  int l15 = lane & 15, quad = lane >> 4;

  const __bf16* keb = (const __bf16*)(ws + WS_KEB) + (unsigned)(n * 100) * 264u;
  const __bf16* w1b = (const __bf16*)(ws + WS_W1B);
  const __bf16* w2pb = (const __bf16*)(ws + WS_W2PB);
  __bf16* biasb = (__bf16*)(ws + WS_BIASB);

  {
    int idx = t * 2;
    int q = idx >> 8, u = idx & 255;
    int c = u >> 7, i = (u & 127) >> 1;
    float p = qpos[(q0 + q) * 2 + c];
    float inv = exp2f((float)i * (-13.287712379549449f / 64.0f));
    float v = p * inv;
    qe_s[idx]     = (__bf16)__sinf(v);
    qe_s[idx + 1] = (__bf16)__cosf(v);
  }

  bf16x8 wfrag[2][8];
#pragma unroll
  for (int ct = 0; ct < 2; ct++)
#pragma unroll
    for (int kc = 0; kc < 8; kc++)
      wfrag[ct][kc] = *(const bf16x8*)(w1b + (unsigned)(w * 32 + ct * 16 + l15) * 256u + kc * 32 + quad * 8);
  float b1v[2][4];
#pragma unroll
  for (int ct = 0; ct < 2; ct++)
#pragma unroll
    for (int r = 0; r < 4; r++) b1v[ct][r] = pos_b1[w * 32 + ct * 16 + quad * 4 + r];
  float b2v[4];
#pragma unroll
  for (int r = 0; r < 4; r++) b2v[r] = pos_b2[(quad * 4 + r) & 7];

  // per-thread gen constants
  bool gact = (t < 448);
  int gkey = t >> 2, gsub = t & 3;
  int gmt = gkey >> 4, gkl = gkey & 15;
  int gkcl = gsub >> 1, gqd0 = (gsub & 1) * 2;
  bf16x8 gk0, gk1, gq0, gq1;

  auto gen_load = [&](int q, int pair) {
    if (gact) {
      int cb = pair * 64 + gsub * 16;
      const __bf16* qp = qe_s + q * 256 + cb;
      gq0 = *(const bf16x8*)qp;
      gq1 = *(const bf16x8*)(qp + 8);
      if (gkey < 100) {
        const __bf16* kp = keb + (unsigned)gkey * 264u + cb;
        gk0 = *(const bf16x8*)kp;
        gk1 = *(const bf16x8*)(kp + 8);
      }
    }
  };
  auto gen_store = [&](int buf) {
    if (gact) {
      bf16x8 fr0, fr1;
      if (gkey < 100) {
#pragma unroll
        for (int jj = 0; jj < 4; jj++) {
          float sk = (float)gk0[2 * jj], ck = (float)gk0[2 * jj + 1];
          float sq = (float)gq0[2 * jj], cq = (float)gq0[2 * jj + 1];
          fr0[2 * jj]     = (__bf16)(sk * cq - ck * sq);
          fr0[2 * jj + 1] = (__bf16)(ck * cq + sk * sq);
          float sk1 = (float)gk1[2 * jj], ck1 = (float)gk1[2 * jj + 1];
          float sq1 = (float)gq1[2 * jj], cq1 = (float)gq1[2 * jj + 1];
          fr1[2 * jj]     = (__bf16)(sk1 * cq1 - ck1 * sq1);
          fr1[2 * jj + 1] = (__bf16)(ck1 * cq1 + sk1 * sq1);
        }
      } else {
#pragma unroll
        for (int jj = 0; jj < 8; jj++) { fr0[jj] = (__bf16)0.f; fr1[jj] = (__bf16)0.f; }
      }
      bf16x8* base = (bf16x8*)smem + buf * 896 + gkcl * 448 + gmt * 64;
      base[gqd0 * 16 + (gkl ^ (gqd0 * 2 + gkcl))]           = fr0;
      base[(gqd0 + 1) * 16 + (gkl ^ (gqd0 * 2 + 2 + gkcl))] = fr1;
    }
  };

  f32x4 zero4; zero4[0] = 0.f; zero4[1] = 0.f; zero4[2] = 0.f; zero4[3] = 0.f;

  __syncthreads();           // qe_s ready
  gen_load(0, 0);
  gen_store(0);
  __syncthreads();

  for (int q = 0; q < 4; q++) {
    f32x4 acc[2][7];
#pragma unroll
    for (int ct = 0; ct < 2; ct++)
#pragma unroll
      for (int mt = 0; mt < 7; mt++) acc[ct][mt] = zero4;

    for (int p = 0; p < 4; p++) {
      int nq = q, npair = p + 1, nbuf = (p + 1) & 1;
      bool have_next = true;
      if (p == 3) {
        if (q < 3) { nq = q + 1; npair = 0; nbuf = 0; }
        else have_next = false;
      }
      if (have_next) gen_load(nq, npair);   // loads in flight across MFMAs

      const bf16x8* pb = (const bf16x8*)smem + (p & 1) * 896;
#pragma unroll
      for (int kh = 0; kh < 2; kh++) {
        int kc = p * 2 + kh;
        bf16x8 pf[7];
#pragma unroll
        for (int mt = 0; mt < 7; mt++)
          pf[mt] = pb[kh * 448 + mt * 64 + quad * 16 + (l15 ^ (quad * 2 + kh))];
#pragma unroll
        for (int mt = 0; mt < 7; mt++) {
          acc[0][mt] = __builtin_amdgcn_mfma_f32_16x16x32_bf16(wfrag[0][kc], pf[mt], acc[0][mt], 0, 0, 0);
          acc[1][mt] = __builtin_amdgcn_mfma_f32_16x16x32_bf16(wfrag[1][kc], pf[mt], acc[1][mt], 0, 0, 0);
        }
      }
      if (have_next) gen_store(nbuf);
      __syncthreads();
    }

#pragma unroll
    for (int ct = 0; ct < 2; ct++)
#pragma unroll
      for (int mt = 0; mt < 7; mt++)
#pragma unroll
        for (int r = 0; r < 4; r++)
          acc[ct][mt][r] = fmaxf(acc[ct][mt][r] + b1v[ct][r], 0.0f);

    auto wreg = [&](int mt, int slot) {
#pragma unroll
      for (int ct = 0; ct < 2; ct++) {
        int qt = ct * 2 + (quad >> 1);
        int j0 = (quad & 1) * 4;
        bf16x4 o;
#pragma unroll
        for (int r = 0; r < 4; r++) o[r] = (__bf16)acc[ct][mt][r];
        *(bf16x4*)(region + slot * 4096 + ((w * 64 + qt * 16 + l15) << 3) + j0) = o;
      }
    };
    auto g2 = [&](int mt, int slot) {
      f32x4 acc2 = zero4;
      const bf16x8* rg = (const bf16x8*)(region + slot * 4096);
#pragma unroll
      for (int s = 0; s < 8; s++) {
        bf16x8 w2f = *(const bf16x8*)(w2pb + (unsigned)l15 * 256u + s * 32 + quad * 8);
        bf16x8 hf = rg[s * 64 + lane];
        acc2 = __builtin_amdgcn_mfma_f32_16x16x32_bf16(w2f, hf, acc2, 0, 0, 0);
      }
      if (quad < 2) {
        int key = mt * 16 + l15;
        if (key < 100) {
          bf16x4 o;
#pragma unroll
          for (int r = 0; r < 4; r++) o[r] = (__bf16)(acc2[r] + b2v[r]);
          *(bf16x4*)(biasb + ((unsigned)(q0 + q) * 100u + key) * 8u + quad * 4) = o;
        }
      }
    };

    wreg(0, 0); wreg(1, 1); wreg(2, 2); wreg(3, 3);
    __syncthreads();
    if (w < 4) g2(w, w);
    __syncthreads();
    wreg(4, 0); wreg(5, 1); wreg(6, 2);
    __syncthreads();
    if (w < 3) g2(4 + w, w);
  }
}

// ---------------------------------------------------------------------------
// attn kernel: per block = 4 queries; transposed (coalesced) weight reads.
__global__ __launch_bounds__(256, 4) void attn_kernel(
    const float* __restrict__ qfeat, const float* __restrict__ qpos,
    const float* __restrict__ kpos,
    const float* __restrict__ out_b, const float* __restrict__ embed_b,
    const float* __restrict__ ptw,
    const float* __restrict__ ws, float* __restrict__ out)
{
  __shared__ float qh_s[4 * 8 * 36];
  __shared__ float attn_s[4 * 8 * 116];
  __shared__ float ctx_s[4 * 264];
  __shared__ float cat_s[4 * 264];
  __shared__ float aw_s[4 * 104];

  int bid = blockIdx.x;
  int qg0 = bid * 4;
  int n = bid / 400;
  int t = threadIdx.x;

  const __bf16* qhb = (const __bf16*)(ws + WS_QHB);
  const __bf16* biasb = (const __bf16*)(ws + WS_BIASB);
  const float* kh = ws + WS_KH;
  const float* vh = ws + WS_VH;
  const float* owt = ws + WS_OWT;
  const float* ewt = ws + WS_EWT;

  for (int i = t; i < 1024; i += 256) {
    int q = i >> 8, c = i & 255;
    qh_s[(q * 8 + (c >> 5)) * 36 + (c & 31)] = (float)qhb[(unsigned)(qg0 + q) * 256u + c];
  }
  __syncthreads();

  for (int i = 0; i < 4; i++) {
    int p = t + i * 256;
    if (p < 800) {
      int k = p >> 3, h = p & 7;
      const float4* kf = (const float4*)(kh + (unsigned)(n * 100 + k) * 256u + h * 32);
      float4 kv[8];
#pragma unroll
      for (int dd = 0; dd < 8; dd++) kv[dd] = kf[dd];
#pragma unroll
      for (int q = 0; q < 4; q++) {
        const float4* qf = (const float4*)(qh_s + (q * 8 + h) * 36);
        float s = (float)biasb[((unsigned)(qg0 + q) * 100u + k) * 8u + h];
#pragma unroll
        for (int dd = 0; dd < 8; dd++) {
          float4 qv = qf[dd];
          s += kv[dd].x * qv.x + kv[dd].y * qv.y + kv[dd].z * qv.z + kv[dd].w * qv.w;
        }
        attn_s[(q * 8 + h) * 116 + k] = s;
      }
    }
  }
  __syncthreads();

  {
    int q = t >> 6, h = (t >> 3) & 7, j = t & 7;
    float* row = attn_s + (q * 8 + h) * 116;
    float mx = -1e30f;
    for (int k = j; k < 100; k += 8) mx = fmaxf(mx, row[k]);
    mx = fmaxf(mx, __shfl_xor(mx, 1, 8));
    mx = fmaxf(mx, __shfl_xor(mx, 2, 8));
    mx = fmaxf(mx, __shfl_xor(mx, 4, 8));
    float sum = 0.f;
    for (int k = j; k < 100; k += 8) { float e = __expf(row[k] - mx); row[k] = e; sum += e; }
    sum += __shfl_xor(sum, 1, 8);
    sum += __shfl_xor(sum, 2, 8);
    sum += __shfl_xor(sum, 4, 8);
    float inv = 1.0f / sum;
    for (int k = j; k < 100; k += 8) row[k] *= inv;
  }
  __syncthreads();

  for (int p = t; p < 416; p += 256) {
    int q = p / 104, k = p % 104;
    if (k < 100) {
      float s = 0.f;
#pragma unroll
      for (int h = 0; h < 8; h++) s += attn_s[(q * 8 + h) * 116 + k];
      aw_s[q * 104 + k] = s * 0.125f;
    }
  }
  {
    int c = t, h = c >> 5;
    float a0 = 0.f, a1 = 0.f, a2 = 0.f, a3 = 0.f;
    const float* vp = vh + (unsigned)(n * 100) * 256u + c;
    const float* r0 = attn_s + (0 * 8 + h) * 116;
    const float* r1 = attn_s + (1 * 8 + h) * 116;
    const float* r2 = attn_s + (2 * 8 + h) * 116;
    const float* r3 = attn_s + (3 * 8 + h) * 116;
#pragma unroll 4
    for (int k = 0; k < 100; k++) {
      float vv = vp[(unsigned)k * 256u];
      a0 = fmaf(r0[k], vv, a0);
      a1 = fmaf(r1[k], vv, a1);
      a2 = fmaf(r2[k], vv, a2);
      a3 = fmaf(r3[k], vv, a3);
    }
    ctx_s[0 * 264 + c] = a0; ctx_s[1 * 264 + c] = a1;
    ctx_s[2 * 264 + c] = a2; ctx_s[3 * 264 + c] = a3;
  }
  __syncthreads();

  if (t < 8) {
    int q = t >> 1, cd = t & 1;
    float qp = qpos[(qg0 + q) * 2 + cd];
    float s = 0.f;
    for (int k = 0; k < 100; k++)
      s = fmaf(aw_s[q * 104 + k], kpos[(n * 100 + k) * 2 + cd] - qp, s);
    float so = __shfl_xor(s, 1, 2);
    if (cd == 0) cat_s[q * 264 + 256] = ptw[0] * s + ptw[1] * so;
    else         cat_s[q * 264 + 257] = ptw[2] * so + ptw[3] * s;
  }

  // out_proj with transposed (coalesced) weights
  {
    int c = t, lane = t & 63;
    float ob = out_b[c];
    float acc0 = ob, acc1 = ob, acc2 = ob, acc3 = ob;
    for (int ch = 0; ch < 4; ch++) {
      float v0 = ctx_s[0 * 264 + ch * 64 + lane];
      float v1 = ctx_s[1 * 264 + ch * 64 + lane];
      float v2 = ctx_s[2 * 264 + ch * 64 + lane];
      float v3 = ctx_s[3 * 264 + ch * 64 + lane];
      const float* wp = owt + (unsigned)(ch * 64) * 256u + c;
#pragma unroll 8
      for (int j2 = 0; j2 < 64; j2++) {
        float wv = wp[(unsigned)j2 * 256u];
        acc0 = fmaf(rdlane(v0, j2), wv, acc0);
        acc1 = fmaf(rdlane(v1, j2), wv, acc1);
        acc2 = fmaf(rdlane(v2, j2), wv, acc2);
        acc3 = fmaf(rdlane(v3, j2), wv, acc3);
      }
    }
    cat_s[0 * 264 + c] = fmaxf(qfeat[(unsigned)(qg0 + 0) * 256u + c] + acc0, 0.f);
    cat_s[1 * 264 + c] = fmaxf(qfeat[(unsigned)(qg0 + 1) * 256u + c] + acc1, 0.f);
    cat_s[2 * 264 + c] = fmaxf(qfeat[(unsigned)(qg0 + 2) * 256u + c] + acc2, 0.f);
    cat_s[3 * 264 + c] = fmaxf(qfeat[(unsigned)(qg0 + 3) * 256u + c] + acc3, 0.f);
  }
  __syncthreads();

  // embed with transposed (coalesced) weights; rows 256/257 = new_pos
  {
    int c = t, lane = t & 63;
    float eb = embed_b[c];
    float acc0 = eb, acc1 = eb, acc2 = eb, acc3 = eb;
    for (int ch = 0; ch < 4; ch++) {
      float v0 = cat_s[0 * 264 + ch * 64 + lane];
      float v1 = cat_s[1 * 264 + ch * 64 + lane];
      float v2 = cat_s[2 * 264 + ch * 64 + lane];
      float v3 = cat_s[3 * 264 + ch * 64 + lane];
      const float* wp = ewt + (unsigned)(ch * 64) * 256u + c;
#pragma unroll 8
      for (int j2 = 0; j2 < 64; j2++) {
        float wv = wp[(unsigned)j2 * 256u];
        acc0 = fmaf(rdlane(v0, j2), wv, acc0);
        acc1 = fmaf(rdlane(v1, j2), wv, acc1);
        acc2 = fmaf(rdlane(v2, j2), wv, acc2);
        acc3 = fmaf(rdlane(v3, j2), wv, acc3);
      }
    }
    float w256 = ewt[256u * 256u + c];
    float w257 = ewt[257u * 256u + c];
    acc0 += cat_s[0 * 264 + 256] * w256 + cat_s[0 * 264 + 257] * w257;
    acc1 += cat_s[1 * 264 + 256] * w256 + cat_s[1 * 264 + 257] * w257;
    acc2 += cat_s[2 * 264 + 256] * w256 + cat_s[2 * 264 + 257] * w257;
    acc3 += cat_s[3 * 264 + 256] * w256 + cat_s[3 * 264 + 257] * w257;
    out[(unsigned)(qg0 + 0) * 256u + c] = fmaxf(acc0, 0.f);
    out[(unsigned)(qg0 + 1) * 256u + c] = fmaxf(acc1, 0.f);
    out[(unsigned)(qg0 + 2) * 256u + c] = fmaxf(acc2, 0.f);
    out[(unsigned)(qg0 + 3) * 256u + c] = fmaxf(acc3, 0.f);
  }
}

// ---------------------------------------------------------------------------
extern "C" void kernel_launch(void* const* d_in, const int* in_sizes, int n_in,
                              void* d_out, int out_size, void* d_ws, size_t ws_size,
                              hipStream_t stream)
{
  const float* query_feature  = (const float*)d_in[0];
  const float* query_position = (const float*)d_in[1];
  const float* key_feature    = (const float*)d_in[2];
  const float* key_position   = (const float*)d_in[3];
  const float* in_proj_w      = (const float*)d_in[4];
  const float* in_proj_b      = (const float*)d_in[5];
  const float* out_proj_w     = (const float*)d_in[6];
  const float* out_proj_b     = (const float*)d_in[7];
  const float* pos_w1         = (const float*)d_in[8];
  const float* pos_b1         = (const float*)d_in[9];
  const float* pos_w2         = (const float*)d_in[10];
  const float* pos_b2         = (const float*)d_in[11];
  const float* pos_trans_w    = (const float*)d_in[12];
  const float* embed_w        = (const float*)d_in[13];
  const float* embed_b        = (const float*)d_in[14];
  float* ws  = (float*)d_ws;
  float* out = (float*)d_out;

  hipLaunchKernelGGL(prep1_kernel, dim3(199), dim3(256), 0, stream,
                     key_position, pos_w1, pos_w2, embed_w, out_proj_w,
                     in_proj_w, ws);
  hipLaunchKernelGGL(prep2_kernel, dim3(432), dim3(256), 0, stream,
                     query_feature, key_feature, in_proj_b, ws);
  hipLaunchKernelGGL(bias_kernel, dim3(800), dim3(512), 0, stream,
                     query_position, pos_b1, pos_b2, ws);
  hipLaunchKernelGGL(attn_kernel, dim3(800), dim3(256), 0, stream,
                     query_feature, query_position, key_position,
                     out_proj_b, embed_b, pos_trans_w,
                     ws, out);
}